// Round 4
// baseline (229.776 us; speedup 1.0000x reference)
//
#include <hip/hip_runtime.h>
#include <hip/hip_bf16.h>
#include <cstdint>
#include <cstddef>

// Problem constants (L=256, C=20, LC=5120, BATCH=1024)
#define LCN 5120
#define BN  1024
#define CN  20

typedef __attribute__((ext_vector_type(4))) float  floatx4;
typedef __attribute__((ext_vector_type(8))) short  shortx8;
typedef __attribute__((ext_vector_type(4))) unsigned short ushortx4;
typedef __attribute__((ext_vector_type(8))) unsigned short ushortx8;

static __device__ __forceinline__ unsigned short f2bf(float f) {
    __hip_bfloat16 h = __float2bfloat16(f);
    return *reinterpret_cast<unsigned short*>(&h);
}

static __device__ __forceinline__ void gload_lds16(const void* g, void* l) {
    __builtin_amdgcn_global_load_lds(
        (const __attribute__((address_space(1))) void*)g,
        (__attribute__((address_space(3))) void*)l,
        16, 0, 0);
}

// ---------------------------------------------------------------------------
// Pass 1 (fused prep), symmetric decomposition:
//   quad[b] = sum_i x[b,i] * ( sum_j Theta[i,j] * (l_j > l_i) * x[b,j] )
// B operand = Theta's OWN ROWS (k = j contiguous) — no transpose.
//
//  blocks [0, 1280): masked streaming bf16 convert (4 rows/block, 1 row/wave):
//      Tb[i][j] = bf16(theta[i*5120+j]) if j >= jmin_i else 0
//      jmin_i = 20*(i/20 + 1); stored for j >= js, js = 512-chunk-aligned
//      start for i's 256-row GEMM n-tile (matches k_quad's c0 formula).
//  blocks [1280, 2304): per batch row b:
//      out[b] = theta_0 + dot(theta_lc, x[b]);  Xb[b,:] = bf16(x[b,:])
// ---------------------------------------------------------------------------
__global__ __launch_bounds__(256) void k_prep(
    const float* __restrict__ th,    // [5120,5120] theta_lclc
    const float* __restrict__ x,     // [1024,5120]
    const float* __restrict__ th0,   // [1]
    const float* __restrict__ thlc,  // [5120]
    unsigned short* __restrict__ Tb, // [5120,5120] bf16 masked theta (row-major)
    unsigned short* __restrict__ Xb, // [1024,5120] bf16 x
    float*          __restrict__ out)
{
    const int tid = threadIdx.x;
    if (blockIdx.x < LCN / 4) {
        // ---- masked streaming convert of theta rows ----
        const int w = tid >> 6, lane = tid & 63;
        const int i = blockIdx.x * 4 + w;                  // row (groups never straddle 256)
        const int lmin = ((i >> 8) << 8) / CN;             // min l in this row's 256-tile
        const int js   = 512 * ((CN * (lmin + 1)) / 512);  // first chunk-aligned col stored
        const int jmin = CN * (i / CN) + CN;               // mask: valid iff j >= jmin
        const float* src = th + (size_t)i * LCN;
        unsigned short* dst = Tb + (size_t)i * LCN;
        // (5120 - js) is a multiple of 512 -> uniform trip count across lanes
        for (int j = js + lane * 8; j < LCN; j += 512) {
            const floatx4 v0 = *reinterpret_cast<const floatx4*>(src + j);
            const floatx4 v1 = *reinterpret_cast<const floatx4*>(src + j + 4);
            ushortx8 o;
#pragma unroll
            for (int e = 0; e < 4; ++e) o[e]     = (j + e     >= jmin) ? f2bf(v0[e]) : (unsigned short)0;
#pragma unroll
            for (int e = 0; e < 4; ++e) o[4 + e] = (j + 4 + e >= jmin) ? f2bf(v1[e]) : (unsigned short)0;
            *reinterpret_cast<ushortx8*>(dst + j) = o;
        }
    } else {
        // ---- linear term + x -> bf16 ----
        const int b = blockIdx.x - LCN / 4;
        const floatx4* xr = reinterpret_cast<const floatx4*>(x + (size_t)b * LCN);
        const floatx4* tr = reinterpret_cast<const floatx4*>(thlc);
        ushortx4* xw = reinterpret_cast<ushortx4*>(Xb + (size_t)b * LCN);
        float s = 0.0f;
        for (int k = tid; k < LCN / 4; k += 256) {
            const floatx4 a = xr[k], t2 = tr[k];
            s += a[0] * t2[0] + a[1] * t2[1] + a[2] * t2[2] + a[3] * t2[3];
            ushortx4 o;
#pragma unroll
            for (int e = 0; e < 4; ++e) o[e] = f2bf(a[e]);
            xw[k] = o;
        }
#pragma unroll
        for (int off = 32; off > 0; off >>= 1) s += __shfl_down(s, off, 64);
        __shared__ float ws4[4];
        if ((tid & 63) == 0) ws4[tid >> 6] = s;
        __syncthreads();
        if (tid == 0) out[b] = th0[0] + ws4[0] + ws4[1] + ws4[2] + ws4[3];
    }
}

// ---------------------------------------------------------------------------
// Pass 2: masked-GEMM + fused dot-reduce.
// 256x256 tile, BK=32, 8 waves (2M x 4N), K-chunks of 512 (NT=16 steps).
// 110 suffix chunks x 4 m-tiles = 440 blocks (grid 448, 8 early-exit) ->
// TWO co-resident blocks/CU (LDS 66KB, 2x fits in 160KB): barrier/vmcnt
// stalls of one block hide under the other's MFMA.  m-siblings of a chunk
// share an XCD (bid%8 RR) so Tb is HBM-fetched once, L2-served 3x.
// 2-phase double-buffered LDS, counted s_waitcnt vmcnt(4) (never 0 mid-loop).
// s_setprio(1) around the MFMA cluster (T5: 2 blocks/CU = phase diversity).
// LDS SEGMENT SWIZZLE (0-conflict): seg g of row r at slot (g+(r>>1))&3;
// readers use seg (kq+(row>>1))&3.
// ---------------------------------------------------------------------------
__global__ __launch_bounds__(512, 2) void k_quad(
    const unsigned short* __restrict__ Xb,   // [1024][5120] bf16
    const unsigned short* __restrict__ Tb,   // [5120][5120] bf16 masked theta
    float*                __restrict__ out)  // [1024]
{
    const int bid  = blockIdx.x;
    const int xcd  = bid & 7;
    const int slot = bid >> 3;
    const int m    = slot & 3;    // M tile (256 rows of batch)
    const int cl   = slot >> 2;   // chunk-local index on this XCD
    int qc = cl * 8 + xcd;        // chunk ordinal 0..109
    if (qc >= 110) return;

    // map chunk ordinal -> (n-tile, k-chunk) over 512-wide suffix chunks
    int n = 0, cs = 0;
    for (int t = 0; t < 20; ++t) {
        const int lmin = (256 * t) / CN;
        const int c0   = (CN * (lmin + 1)) / 512;
        const int cnt  = 10 - c0;
        if (qc < cnt) { n = t; cs = c0 + qc; break; }
        qc -= cnt;
    }
    const int b0 = m * 256;
    const int n0 = n * 256;
    const int k0 = cs * 512;

    __shared__ unsigned short As[2 * 256 * 32];   // dbuf A: [row b][4 swizzled 16B segs]
    __shared__ unsigned short Bs[2 * 256 * 32];   // dbuf B: [row i][4 swizzled 16B segs]
    __shared__ float partial[256];

    const int tid  = threadIdx.x;
    const int lane = tid & 63;
    const int w    = tid >> 6;        // wave 0..7
    const int wm   = w & 1;           // M half (128 rows)
    const int wn   = w >> 1;          // N quarter (64 cols)
    const int lrow = lane & 15;
    const int kq   = lane >> 4;       // 0..3

    if (tid < 256) partial[tid] = 0.0f;

    floatx4 acc[8][4];
#pragma unroll
    for (int mt = 0; mt < 8; ++mt)
#pragma unroll
        for (int nt = 0; nt < 4; ++nt) acc[mt][nt] = (floatx4)0.0f;

    // precompute swizzled fragment offsets (ushort units)
    int aoff[8], boff[4];
#pragma unroll
    for (int mt = 0; mt < 8; ++mt) {
        const int row = wm * 128 + mt * 16 + lrow;
        aoff[mt] = row * 32 + (((kq + (row >> 1)) & 3) << 3);
    }
#pragma unroll
    for (int nt = 0; nt < 4; ++nt) {
        const int row = wn * 64 + nt * 16 + lrow;
        boff[nt] = row * 32 + (((kq + (row >> 1)) & 3) << 3);
    }

    // stage one 256x32 A-tile + B-tile into buffer `buf`; 1024 16B segs each,
    // 512 threads -> 2 segs/thread/array (4 gload_lds16 per thread total).
    // LDS dest is linear (wave-uniform base + lane*16); the swizzle is applied
    // by permuting the GLOBAL source segment (inverse swizzle).
#define STAGE(buf, kc) do {                                                       \
    _Pragma("unroll")                                                             \
    for (int t = 0; t < 2; ++t) {                                                 \
        const int s    = t * 512 + tid;                                           \
        const int row  = s >> 2;                                                  \
        const int gseg = ((s & 3) - (row >> 1)) & 3;                              \
        char* la = (char*)As + (buf) * 16384 + (size_t)(t * 512 + w * 64) * 16;   \
        char* lb = (char*)Bs + (buf) * 16384 + (size_t)(t * 512 + w * 64) * 16;   \
        gload_lds16(Xb + (size_t)(b0 + row) * LCN + (kc) + gseg * 8, la);         \
        gload_lds16(Tb + (size_t)(n0 + row) * LCN + (kc) + gseg * 8, lb);         \
    }                                                                             \
} while (0)

    STAGE(0, k0);                               // prologue: 4 loads in flight
#pragma unroll 2
    for (int kk = 0; kk < 16; ++kk) {
        const int cur = kk & 1;
        if (kk < 15) {
            STAGE(cur ^ 1, k0 + (kk + 1) * 32); // issue next tile (4 more loads)
            asm volatile("s_waitcnt vmcnt(4)" ::: "memory");  // wait current only
        } else {
            asm volatile("s_waitcnt vmcnt(0)" ::: "memory");
        }
        __builtin_amdgcn_s_barrier();           // all waves' current loads landed

        const unsigned short* Ab = As + cur * 8192;
        const unsigned short* Bb = Bs + cur * 8192;
        shortx8 bf4[4];
#pragma unroll
        for (int nt = 0; nt < 4; ++nt)
            bf4[nt] = *reinterpret_cast<const shortx8*>(Bb + boff[nt]);
        shortx8 af8[8];
#pragma unroll
        for (int mt = 0; mt < 8; ++mt)
            af8[mt] = *reinterpret_cast<const shortx8*>(Ab + aoff[mt]);
        __builtin_amdgcn_s_setprio(1);
#pragma unroll
        for (int mt = 0; mt < 8; ++mt)
#pragma unroll
            for (int nt = 0; nt < 4; ++nt)
                acc[mt][nt] = __builtin_amdgcn_mfma_f32_16x16x32_bf16(af8[mt], bf4[nt], acc[mt][nt], 0, 0, 0);
        __builtin_amdgcn_s_setprio(0);

        __builtin_amdgcn_s_barrier();           // done reading buf before overwrite
    }
#undef STAGE

    // Epilogue: C/D layout col = lane&15 (i), row = (lane>>4)*4 + reg (b)
#pragma unroll
    for (int mt = 0; mt < 8; ++mt) {
#pragma unroll
        for (int r = 0; r < 4; ++r) {
            const int b = b0 + wm * 128 + mt * 16 + kq * 4 + r;
            float s = 0.0f;
#pragma unroll
            for (int nt = 0; nt < 4; ++nt) {
                const int i = n0 + wn * 64 + nt * 16 + lrow;
                const __hip_bfloat16 hv = *reinterpret_cast<const __hip_bfloat16*>(&Xb[(size_t)b * LCN + i]);
                s += acc[mt][nt][r] * __bfloat162float(hv);
            }
            s += __shfl_xor(s, 1, 64);
            s += __shfl_xor(s, 2, 64);
            s += __shfl_xor(s, 4, 64);
            s += __shfl_xor(s, 8, 64);
            if (lrow == 0) atomicAdd(&partial[b - b0], s);
        }
    }
    __syncthreads();
    if (tid < 256) atomicAdd(&out[b0 + tid], partial[tid]);
}

// ---------------------------------------------------------------------------
extern "C" void kernel_launch(void* const* d_in, const int* in_sizes, int n_in,
                              void* d_out, int out_size, void* d_ws, size_t ws_size,
                              hipStream_t stream) {
    const float* x      = (const float*)d_in[0];  // [1024, 5120]
    const float* th0    = (const float*)d_in[1];  // [1]
    const float* thlc   = (const float*)d_in[2];  // [5120]
    const float* thlclc = (const float*)d_in[3];  // [5120, 5120]
    float* out = (float*)d_out;                   // [1024]

    // ws layout: Tb (bf16 5120x5120 = 52.4 MB) | Xb (bf16 1024x5120 = 10.5 MB)
    unsigned short* Tb = (unsigned short*)d_ws;
    unsigned short* Xb = (unsigned short*)((char*)d_ws + (size_t)LCN * LCN * 2);

    // fused prep: 1280 theta-convert blocks + 1024 init blocks
    k_prep<<<dim3(LCN / 4 + BN), 256, 0, stream>>>(thlclc, x, th0, thlc, Tb, Xb, out);

    // 110 chunks x 4 m-tiles; 14 chunk-slots per XCD: grid = 14*4*8 = 448
    k_quad<<<dim3(448), 512, 0, stream>>>(Xb, Tb, out);
}

// Round 5
// 212.870 us; speedup vs baseline: 1.0794x; 1.0794x over previous
//
#include <hip/hip_runtime.h>
#include <hip/hip_bf16.h>
#include <cstdint>
#include <cstddef>

// Problem constants (L=256, C=20, LC=5120, BATCH=1024)
#define LCN 5120
#define BN  1024
#define CN  20

typedef __attribute__((ext_vector_type(4))) float  floatx4;
typedef __attribute__((ext_vector_type(8))) short  shortx8;
typedef __attribute__((ext_vector_type(4))) unsigned short ushortx4;
typedef __attribute__((ext_vector_type(8))) unsigned short ushortx8;

static __device__ __forceinline__ unsigned short f2bf(float f) {
    __hip_bfloat16 h = __float2bfloat16(f);
    return *reinterpret_cast<unsigned short*>(&h);
}

static __device__ __forceinline__ void gload_lds16(const void* g, void* l) {
    __builtin_amdgcn_global_load_lds(
        (const __attribute__((address_space(1))) void*)g,
        (__attribute__((address_space(3))) void*)l,
        16, 0, 0);
}

// ---------------------------------------------------------------------------
// Pass 1 (fused prep), symmetric decomposition:
//   quad[b] = sum_i x[b,i] * ( sum_j Theta[i,j] * (l_j > l_i) * x[b,j] )
// B operand = Theta's OWN ROWS (k = j contiguous) — no transpose.
//
//  blocks [0, 1280): masked streaming bf16 convert (4 rows/block, 1 row/wave):
//      Tb[i][j] = bf16(theta[i*5120+j]) if j >= jmin_i else 0
//      jmin_i = 20*(i/20 + 1); stored for j >= js, js = 1024-chunk-aligned
//      start for i's 256-row GEMM n-tile (matches k_quad's c0 formula).
//  blocks [1280, 2304): per batch row b:
//      out[b] = theta_0 + dot(theta_lc, x[b]);  Xb[b,:] = bf16(x[b,:])
// ---------------------------------------------------------------------------
__global__ __launch_bounds__(256) void k_prep(
    const float* __restrict__ th,    // [5120,5120] theta_lclc
    const float* __restrict__ x,     // [1024,5120]
    const float* __restrict__ th0,   // [1]
    const float* __restrict__ thlc,  // [5120]
    unsigned short* __restrict__ Tb, // [5120,5120] bf16 masked theta (row-major)
    unsigned short* __restrict__ Xb, // [1024,5120] bf16 x
    float*          __restrict__ out)
{
    const int tid = threadIdx.x;
    if (blockIdx.x < LCN / 4) {
        // ---- masked streaming convert of theta rows ----
        const int w = tid >> 6, lane = tid & 63;
        const int i = blockIdx.x * 4 + w;                  // row (groups never straddle 256)
        const int lmin = ((i >> 8) << 8) / CN;             // min l in this row's 256-tile
        const int js   = 1024 * ((CN * (lmin + 1)) / 1024);// first chunk-aligned col stored
        const int jmin = CN * (i / CN) + CN;               // mask: valid iff j >= jmin
        const float* src = th + (size_t)i * LCN;
        unsigned short* dst = Tb + (size_t)i * LCN;
        // (5120 - js) is a multiple of 512 -> uniform trip count across lanes
        for (int j = js + lane * 8; j < LCN; j += 512) {
            const floatx4 v0 = *reinterpret_cast<const floatx4*>(src + j);
            const floatx4 v1 = *reinterpret_cast<const floatx4*>(src + j + 4);
            ushortx8 o;
#pragma unroll
            for (int e = 0; e < 4; ++e) o[e]     = (j + e     >= jmin) ? f2bf(v0[e]) : (unsigned short)0;
#pragma unroll
            for (int e = 0; e < 4; ++e) o[4 + e] = (j + 4 + e >= jmin) ? f2bf(v1[e]) : (unsigned short)0;
            *reinterpret_cast<ushortx8*>(dst + j) = o;
        }
    } else {
        // ---- linear term + x -> bf16 ----
        const int b = blockIdx.x - LCN / 4;
        const floatx4* xr = reinterpret_cast<const floatx4*>(x + (size_t)b * LCN);
        const floatx4* tr = reinterpret_cast<const floatx4*>(thlc);
        ushortx4* xw = reinterpret_cast<ushortx4*>(Xb + (size_t)b * LCN);
        float s = 0.0f;
        for (int k = tid; k < LCN / 4; k += 256) {
            const floatx4 a = xr[k], t2 = tr[k];
            s += a[0] * t2[0] + a[1] * t2[1] + a[2] * t2[2] + a[3] * t2[3];
            ushortx4 o;
#pragma unroll
            for (int e = 0; e < 4; ++e) o[e] = f2bf(a[e]);
            xw[k] = o;
        }
#pragma unroll
        for (int off = 32; off > 0; off >>= 1) s += __shfl_down(s, off, 64);
        __shared__ float ws4[4];
        if ((tid & 63) == 0) ws4[tid >> 6] = s;
        __syncthreads();
        if (tid == 0) out[b] = th0[0] + ws4[0] + ws4[1] + ws4[2] + ws4[3];
    }
}

// ---------------------------------------------------------------------------
// Pass 2: masked-GEMM + fused dot-reduce.
// 256x256 tile, BK=32, 8 waves (2M x 4N), K-chunks of 1024 (NT=32 steps).
// 60 suffix chunks x 4 m-tiles = 240 blocks (grid 256, 16 early-exit);
// m-siblings of a chunk share an XCD (bid%8 RR) -> Tb HBM-fetched once.
//
// 4-DEEP LDS PIPELINE (latency fix for R4's 45µs of exposed stalls):
//   4 buffers (129 KB LDS, 1 block/CU which is all we get anyway);
//   stage kk+3 issued at step kk -> ~3 MFMA-phases (~1000 cyc) cover HBM
//   latency; steady-state wait vmcnt(8) (= 2 future stages x 4 loads).
//   ONE barrier per step: the stage issued at step kk writes buf (kk-1)&3,
//   whose readers all completed before reaching this step's barrier (their
//   ds_reads were consumed by MFMAs issued before the barrier).
// LDS SEGMENT SWIZZLE (0-conflict): seg g of row r at slot (g+(r>>1))&3;
// readers use seg (kq+(row>>1))&3.
// ---------------------------------------------------------------------------
__global__ __launch_bounds__(512, 2) void k_quad(
    const unsigned short* __restrict__ Xb,   // [1024][5120] bf16
    const unsigned short* __restrict__ Tb,   // [5120][5120] bf16 masked theta
    float*                __restrict__ out)  // [1024]
{
    const int bid  = blockIdx.x;
    const int xcd  = bid & 7;
    const int slot = bid >> 3;
    const int m    = slot & 3;    // M tile (256 rows of batch)
    const int cl   = slot >> 2;   // chunk-local index on this XCD
    int qc = cl * 8 + xcd;        // chunk ordinal 0..59
    if (qc >= 60) return;

    // map chunk ordinal -> (n-tile, k-chunk) over 1024-wide suffix chunks
    int n = 0, cs = 0;
    for (int t = 0; t < 20; ++t) {
        const int lmin = (256 * t) / CN;
        const int c0   = (CN * (lmin + 1)) / 1024;
        const int cnt  = 5 - c0;
        if (qc < cnt) { n = t; cs = c0 + qc; break; }
        qc -= cnt;
    }
    const int b0 = m * 256;
    const int n0 = n * 256;
    const int k0 = cs * 1024;

    __shared__ unsigned short As[4 * 256 * 32];   // 4-buf A: [row b][4 swizzled 16B segs]
    __shared__ unsigned short Bs[4 * 256 * 32];   // 4-buf B: [row i][4 swizzled 16B segs]
    __shared__ float partial[256];

    const int tid  = threadIdx.x;
    const int lane = tid & 63;
    const int w    = tid >> 6;        // wave 0..7
    const int wm   = w & 1;           // M half (128 rows)
    const int wn   = w >> 1;          // N quarter (64 cols)
    const int lrow = lane & 15;
    const int kq   = lane >> 4;       // 0..3

    if (tid < 256) partial[tid] = 0.0f;

    floatx4 acc[8][4];
#pragma unroll
    for (int mt = 0; mt < 8; ++mt)
#pragma unroll
        for (int nt = 0; nt < 4; ++nt) acc[mt][nt] = (floatx4)0.0f;

    // precompute swizzled fragment offsets (ushort units)
    int aoff[8], boff[4];
#pragma unroll
    for (int mt = 0; mt < 8; ++mt) {
        const int row = wm * 128 + mt * 16 + lrow;
        aoff[mt] = row * 32 + (((kq + (row >> 1)) & 3) << 3);
    }
#pragma unroll
    for (int nt = 0; nt < 4; ++nt) {
        const int row = wn * 64 + nt * 16 + lrow;
        boff[nt] = row * 32 + (((kq + (row >> 1)) & 3) << 3);
    }

    // stage one 256x32 A-tile + B-tile into buffer `buf`; 1024 16B segs each,
    // 512 threads -> 2 segs/thread/array (4 gload_lds16 per thread per stage).
    // LDS dest is linear (wave-uniform base + lane*16); the swizzle is applied
    // by permuting the GLOBAL source segment (inverse swizzle).
#define STAGE(buf, kc) do {                                                       \
    _Pragma("unroll")                                                             \
    for (int t = 0; t < 2; ++t) {                                                 \
        const int s    = t * 512 + tid;                                           \
        const int row  = s >> 2;                                                  \
        const int gseg = ((s & 3) - (row >> 1)) & 3;                              \
        char* la = (char*)As + (buf) * 16384 + (size_t)(t * 512 + w * 64) * 16;   \
        char* lb = (char*)Bs + (buf) * 16384 + (size_t)(t * 512 + w * 64) * 16;   \
        gload_lds16(Xb + (size_t)(b0 + row) * LCN + (kc) + gseg * 8, la);         \
        gload_lds16(Tb + (size_t)(n0 + row) * LCN + (kc) + gseg * 8, lb);         \
    }                                                                             \
} while (0)

    // per-step body: wait own stage-kk loads -> barrier (everyone's landed,
    // and everyone finished reading buf (kk-1)&3) -> issue stage kk+3 ->
    // fragment reads -> MFMA.  VM is the literal vmcnt for this step.
#define BODY(kk, PAR, VM) do {                                                     \
    asm volatile("s_waitcnt vmcnt(" #VM ")" ::: "memory");                         \
    __builtin_amdgcn_s_barrier();                                                  \
    if ((kk) + 3 < 32) STAGE(((PAR) + 3) & 3, k0 + ((kk) + 3) * 32);               \
    shortx8 bf4[4], af8[8];                                                        \
    _Pragma("unroll")                                                              \
    for (int nt = 0; nt < 4; ++nt)                                                 \
        bf4[nt] = *reinterpret_cast<const shortx8*>(Bs + (PAR) * 8192 + boff[nt]); \
    _Pragma("unroll")                                                              \
    for (int mt = 0; mt < 8; ++mt)                                                 \
        af8[mt] = *reinterpret_cast<const shortx8*>(As + (PAR) * 8192 + aoff[mt]); \
    __builtin_amdgcn_s_setprio(1);                                                 \
    _Pragma("unroll")                                                              \
    for (int mt = 0; mt < 8; ++mt)                                                 \
        _Pragma("unroll")                                                          \
        for (int nt = 0; nt < 4; ++nt)                                             \
            acc[mt][nt] = __builtin_amdgcn_mfma_f32_16x16x32_bf16(af8[mt], bf4[nt], acc[mt][nt], 0, 0, 0); \
    __builtin_amdgcn_s_setprio(0);                                                 \
} while (0)

    // prologue: 3 stages in flight (12 loads/wave outstanding)
    STAGE(0, k0);
    STAGE(1, k0 + 32);
    STAGE(2, k0 + 64);

    for (int kk = 0; kk < 28; kk += 4) {
        BODY(kk + 0, 0, 8);
        BODY(kk + 1, 1, 8);
        BODY(kk + 2, 2, 8);
        BODY(kk + 3, 3, 8);
    }
    // tail: steps 28..31 (stage 31 issued at 28; waits drain 8 -> 4 -> 0)
    BODY(28, 0, 8);
    BODY(29, 1, 8);
    BODY(30, 2, 4);
    BODY(31, 3, 0);
#undef BODY
#undef STAGE

    // Epilogue: C/D layout col = lane&15 (i), row = (lane>>4)*4 + reg (b)
#pragma unroll
    for (int mt = 0; mt < 8; ++mt) {
#pragma unroll
        for (int r = 0; r < 4; ++r) {
            const int b = b0 + wm * 128 + mt * 16 + kq * 4 + r;
            float s = 0.0f;
#pragma unroll
            for (int nt = 0; nt < 4; ++nt) {
                const int i = n0 + wn * 64 + nt * 16 + lrow;
                const __hip_bfloat16 hv = *reinterpret_cast<const __hip_bfloat16*>(&Xb[(size_t)b * LCN + i]);
                s += acc[mt][nt][r] * __bfloat162float(hv);
            }
            s += __shfl_xor(s, 1, 64);
            s += __shfl_xor(s, 2, 64);
            s += __shfl_xor(s, 4, 64);
            s += __shfl_xor(s, 8, 64);
            if (lrow == 0) atomicAdd(&partial[b - b0], s);
        }
    }
    __syncthreads();
    if (tid < 256) atomicAdd(&out[b0 + tid], partial[tid]);
}

// ---------------------------------------------------------------------------
extern "C" void kernel_launch(void* const* d_in, const int* in_sizes, int n_in,
                              void* d_out, int out_size, void* d_ws, size_t ws_size,
                              hipStream_t stream) {
    const float* x      = (const float*)d_in[0];  // [1024, 5120]
    const float* th0    = (const float*)d_in[1];  // [1]
    const float* thlc   = (const float*)d_in[2];  // [5120]
    const float* thlclc = (const float*)d_in[3];  // [5120, 5120]
    float* out = (float*)d_out;                   // [1024]

    // ws layout: Tb (bf16 5120x5120 = 52.4 MB) | Xb (bf16 1024x5120 = 10.5 MB)
    unsigned short* Tb = (unsigned short*)d_ws;
    unsigned short* Xb = (unsigned short*)((char*)d_ws + (size_t)LCN * LCN * 2);

    // fused prep: 1280 theta-convert blocks + 1024 init blocks
    k_prep<<<dim3(LCN / 4 + BN), 256, 0, stream>>>(thlclc, x, th0, thlc, Tb, Xb, out);

    // 60 chunks x 4 m-tiles, padded to 8 chunk-slots per XCD: 8*8*4 = 256 blocks
    k_quad<<<dim3(256), 512, 0, stream>>>(Xb, Tb, out);
}